// Round 1
// baseline (10977.589 us; speedup 1.0000x reference)
//
#include <hip/hip_runtime.h>

#define N_NODES 100000
#define IN_F 256
#define OUT_F 256

typedef float f32x4 __attribute__((ext_vector_type(4)));
typedef __bf16 bf16x8 __attribute__((ext_vector_type(8)));

// Transpose + convert W[k][n] (fp32) -> Wt[n][k] (bf16) so the MFMA B-fragment
// (8 consecutive k at fixed n) is one contiguous 16B load.
__global__ __launch_bounds__(256) void prep_w_kernel(const float* __restrict__ W,
                                                     __bf16* __restrict__ Wt) {
    int n = blockIdx.x;   // output column
    int k = threadIdx.x;  // input feature
    Wt[n * IN_F + k] = (__bf16)W[k * OUT_F + n];
}

// h = x @ W + bias.  One wave per 16x16 output tile, K=256 in 8 MFMA steps.
// A-frag: x[mt*16 + (lane&15)][k0 + (lane>>4)*8 + j]  (8 consecutive fp32, cvt->bf16)
// B-frag: Wt[nt*16 + (lane&15)][k0 + (lane>>4)*8 + j] (contiguous bf16x8)
// C/D   : h[mt*16 + (lane>>4)*4 + r][nt*16 + (lane&15)]
__global__ __launch_bounds__(256) void gemm_kernel(const float* __restrict__ x,
                                                   const __bf16* __restrict__ Wt,
                                                   const float* __restrict__ bias,
                                                   float* __restrict__ h) {
    int wave = (blockIdx.x << 2) | (threadIdx.x >> 6);
    int lane = threadIdx.x & 63;
    int mt = wave >> 4;   // 6250 m-tiles (100000/16)
    int nt = wave & 15;   // 16 n-tiles (256/16)
    int r16 = lane & 15;
    int quad = lane >> 4;

    const float*  xp = x  + (long)(mt * 16 + r16) * IN_F + quad * 8;
    const __bf16* wp = Wt + (long)(nt * 16 + r16) * IN_F + quad * 8;

    f32x4 acc = {0.f, 0.f, 0.f, 0.f};
#pragma unroll
    for (int k0 = 0; k0 < IN_F; k0 += 32) {
        f32x4 x0 = *(const f32x4*)(xp + k0);
        f32x4 x1 = *(const f32x4*)(xp + k0 + 4);
        bf16x8 a;
        a[0] = (__bf16)x0[0]; a[1] = (__bf16)x0[1];
        a[2] = (__bf16)x0[2]; a[3] = (__bf16)x0[3];
        a[4] = (__bf16)x1[0]; a[5] = (__bf16)x1[1];
        a[6] = (__bf16)x1[2]; a[7] = (__bf16)x1[3];
        bf16x8 b = *(const bf16x8*)(wp + k0);
        acc = __builtin_amdgcn_mfma_f32_16x16x32_bf16(a, b, acc, 0, 0, 0);
    }
    float bv = bias[nt * 16 + r16];
    float* hp = h + (long)(mt * 16 + quad * 4) * OUT_F + nt * 16 + r16;
#pragma unroll
    for (int r = 0; r < 4; ++r) hp[(long)r * OUT_F] = acc[r] + bv;
}

// out[row[e]] += val[e] * h[col[e]].  One wave per edge, float4 per lane
// (64 lanes x 16B = 1KB row).  Device-scope fp32 atomics (cross-XCD safe).
__global__ __launch_bounds__(256) void spmm_kernel(const int* __restrict__ rows,
                                                   const int* __restrict__ cols,
                                                   const float* __restrict__ vals,
                                                   const float* __restrict__ h,
                                                   float* __restrict__ out, int nE) {
    int e = (blockIdx.x << 2) | (threadIdx.x >> 6);
    if (e >= nE) return;
    int lane = threadIdx.x & 63;
    int c = cols[e];
    int r = rows[e];
    float v = vals[e];
    f32x4 hv = ((const f32x4*)(h + (size_t)c * OUT_F))[lane];
    float* op = out + (size_t)r * OUT_F + lane * 4;
    atomicAdd(op + 0, v * hv[0]);
    atomicAdd(op + 1, v * hv[1]);
    atomicAdd(op + 2, v * hv[2]);
    atomicAdd(op + 3, v * hv[3]);
}

extern "C" void kernel_launch(void* const* d_in, const int* in_sizes, int n_in,
                              void* d_out, int out_size, void* d_ws, size_t ws_size,
                              hipStream_t stream) {
    const float* x         = (const float*)d_in[0];
    const int*   edge_rows = (const int*)d_in[1];
    const int*   edge_cols = (const int*)d_in[2];
    const float* adj_vals  = (const float*)d_in[3];
    const float* weight    = (const float*)d_in[4];
    const float* bias      = (const float*)d_in[5];
    float* out = (float*)d_out;
    int nE = in_sizes[1];

    // Workspace layout: h (fp32, 100000*256*4 = 102.4 MB) | Wt (bf16, 128 KB)
    float*  h  = (float*)d_ws;
    __bf16* Wt = (__bf16*)((char*)d_ws + (size_t)N_NODES * OUT_F * sizeof(float));

    prep_w_kernel<<<OUT_F, IN_F, 0, stream>>>(weight, Wt);
    hipMemsetAsync(d_out, 0, (size_t)out_size * sizeof(float), stream);

    // 6250 m-tiles * 16 n-tiles = 100000 waves = 25000 blocks of 4 waves
    gemm_kernel<<<(N_NODES / 16) * (OUT_F / 16) / 4, 256, 0, stream>>>(x, Wt, bias, h);

    int eBlocks = (nE + 3) / 4;
    spmm_kernel<<<eBlocks, 256, 0, stream>>>(edge_rows, edge_cols, adj_vals, h, out, nE);
}

// Round 2
// 1007.806 us; speedup vs baseline: 10.8926x; 10.8926x over previous
//
#include <hip/hip_runtime.h>

#define N_NODES 100000
#define IN_F 256
#define OUT_F 256
#define NROWS N_NODES
#define NBLK ((NROWS + 255) / 256)   // 391 scan blocks

typedef float f32x4 __attribute__((ext_vector_type(4)));
typedef __bf16 bf16x8 __attribute__((ext_vector_type(8)));
typedef __bf16 bf16x4 __attribute__((ext_vector_type(4)));

// ---------- W transpose + bf16 convert: Wt[n][k] ----------
__global__ __launch_bounds__(256) void prep_w_kernel(const float* __restrict__ W,
                                                     __bf16* __restrict__ Wt) {
    int n = blockIdx.x;
    int k = threadIdx.x;
    Wt[n * IN_F + k] = (__bf16)W[k * OUT_F + n];
}

// ---------- h = x @ W + bias (bf16 output) ----------
// One wave per 16x16 tile. A: x rows (fp32->bf16), B: Wt rows (bf16x8).
// C/D layout: col=lane&15, row=(lane>>4)*4+reg.
__global__ __launch_bounds__(256) void gemm_kernel(const float* __restrict__ x,
                                                   const __bf16* __restrict__ Wt,
                                                   const float* __restrict__ bias,
                                                   __bf16* __restrict__ h) {
    int wave = (blockIdx.x << 2) | (threadIdx.x >> 6);
    int lane = threadIdx.x & 63;
    int mt = wave >> 4;
    int nt = wave & 15;
    int r16 = lane & 15;
    int quad = lane >> 4;

    const float*  xp = x  + (long)(mt * 16 + r16) * IN_F + quad * 8;
    const __bf16* wp = Wt + (long)(nt * 16 + r16) * IN_F + quad * 8;

    f32x4 acc = {0.f, 0.f, 0.f, 0.f};
#pragma unroll
    for (int k0 = 0; k0 < IN_F; k0 += 32) {
        f32x4 x0 = *(const f32x4*)(xp + k0);
        f32x4 x1 = *(const f32x4*)(xp + k0 + 4);
        bf16x8 a;
        a[0] = (__bf16)x0[0]; a[1] = (__bf16)x0[1];
        a[2] = (__bf16)x0[2]; a[3] = (__bf16)x0[3];
        a[4] = (__bf16)x1[0]; a[5] = (__bf16)x1[1];
        a[6] = (__bf16)x1[2]; a[7] = (__bf16)x1[3];
        bf16x8 b = *(const bf16x8*)(wp + k0);
        acc = __builtin_amdgcn_mfma_f32_16x16x32_bf16(a, b, acc, 0, 0, 0);
    }
    float bv = bias[nt * 16 + r16];
    __bf16* hp = h + (long)(mt * 16 + quad * 4) * OUT_F + nt * 16 + r16;
#pragma unroll
    for (int r = 0; r < 4; ++r) hp[(long)r * OUT_F] = (__bf16)(acc[r] + bv);
}

// ---------- CSR build ----------
__global__ __launch_bounds__(256) void count_kernel(const int* __restrict__ rows,
                                                    int* __restrict__ deg, int nE) {
    int e = blockIdx.x * 256 + threadIdx.x;
    if (e < nE) atomicAdd(&deg[rows[e]], 1);
}

__global__ __launch_bounds__(256) void partial_kernel(const int* __restrict__ deg,
                                                      int* __restrict__ partial) {
    __shared__ int s[256];
    int i = blockIdx.x * 256 + threadIdx.x;
    s[threadIdx.x] = (i < NROWS) ? deg[i] : 0;
    __syncthreads();
    for (int d = 128; d > 0; d >>= 1) {
        if (threadIdx.x < d) s[threadIdx.x] += s[threadIdx.x + d];
        __syncthreads();
    }
    if (threadIdx.x == 0) partial[blockIdx.x] = s[0];
}

__global__ __launch_bounds__(512) void scan_partial_kernel(const int* __restrict__ partial,
                                                           int* __restrict__ blockoff,
                                                           int* __restrict__ row_start, int nE) {
    __shared__ int s[512];
    int t = threadIdx.x;
    int v = (t < NBLK) ? partial[t] : 0;
    s[t] = v;
    __syncthreads();
    for (int d = 1; d < 512; d <<= 1) {
        int u = (t >= d) ? s[t - d] : 0;
        __syncthreads();
        s[t] += u;
        __syncthreads();
    }
    if (t < NBLK) blockoff[t] = s[t] - v;   // exclusive block offset
    if (t == 0) row_start[NROWS] = nE;
}

__global__ __launch_bounds__(256) void scan_rows_kernel(const int* __restrict__ deg,
                                                        const int* __restrict__ blockoff,
                                                        int* __restrict__ row_start) {
    __shared__ int s[256];
    int t = threadIdx.x;
    int i = blockIdx.x * 256 + t;
    int v = (i < NROWS) ? deg[i] : 0;
    s[t] = v;
    __syncthreads();
    for (int d = 1; d < 256; d <<= 1) {
        int u = (t >= d) ? s[t - d] : 0;
        __syncthreads();
        s[t] += u;
        __syncthreads();
    }
    if (i < NROWS) row_start[i] = blockoff[blockIdx.x] + s[t] - v;
}

__global__ __launch_bounds__(256) void scatter_kernel(const int* __restrict__ rows,
                                                      const int* __restrict__ cols,
                                                      const float* __restrict__ vals,
                                                      const int* __restrict__ row_start,
                                                      int* __restrict__ cursor,
                                                      int2* __restrict__ sorted, int nE) {
    int e = blockIdx.x * 256 + threadIdx.x;
    if (e >= nE) return;
    int r = rows[e];
    int pos = row_start[r] + atomicAdd(&cursor[r], 1);
    sorted[pos] = make_int2(cols[e], __float_as_int(vals[e]));
}

// ---------- SpMM: one wave per row, register accumulation, no atomics ----------
__global__ __launch_bounds__(256) void spmm_csr_kernel(const int* __restrict__ row_start,
                                                       const int2* __restrict__ sorted,
                                                       const __bf16* __restrict__ h,
                                                       float* __restrict__ out) {
    int r = (blockIdx.x << 2) | (threadIdx.x >> 6);
    int lane = threadIdx.x & 63;
    int e0 = row_start[r];
    int e1 = row_start[r + 1];
    f32x4 acc = {0.f, 0.f, 0.f, 0.f};
    for (int e = e0; e < e1; ++e) {
        int2 cv = sorted[e];                       // wave-uniform -> broadcast
        float v = __int_as_float(cv.y);
        bf16x4 hv = ((const bf16x4*)(h + (size_t)cv.x * OUT_F))[lane];
        acc[0] += v * (float)hv[0];
        acc[1] += v * (float)hv[1];
        acc[2] += v * (float)hv[2];
        acc[3] += v * (float)hv[3];
    }
    ((f32x4*)(out + (size_t)r * OUT_F))[lane] = acc;
}

extern "C" void kernel_launch(void* const* d_in, const int* in_sizes, int n_in,
                              void* d_out, int out_size, void* d_ws, size_t ws_size,
                              hipStream_t stream) {
    const float* x         = (const float*)d_in[0];
    const int*   edge_rows = (const int*)d_in[1];
    const int*   edge_cols = (const int*)d_in[2];
    const float* adj_vals  = (const float*)d_in[3];
    const float* weight    = (const float*)d_in[4];
    const float* bias      = (const float*)d_in[5];
    float* out = (float*)d_out;
    int nE = in_sizes[1];

    // ---- workspace layout (~78 MB total) ----
    char* w = (char*)d_ws;
    __bf16* h  = (__bf16*)w;  w += (size_t)N_NODES * OUT_F * sizeof(__bf16);   // 51.2 MB
    __bf16* Wt = (__bf16*)w;  w += (size_t)IN_F * OUT_F * sizeof(__bf16);      // 128 KB
    int* deg       = (int*)w; w += (size_t)NROWS * 4;                          // 400 KB
    int* cursor    = (int*)w; w += (size_t)NROWS * 4;                          // 400 KB (contiguous w/ deg)
    int* row_start = (int*)w; w += (size_t)(NROWS + 1) * 4 + 12;               // 400 KB + pad
    int* partial   = (int*)w; w += (size_t)NBLK * 4;
    int* blockoff  = (int*)w; w += (size_t)NBLK * 4 + 8;
    int2* sorted   = (int2*)w;                                                 // 25.6 MB

    // zero deg + cursor (contiguous)
    hipMemsetAsync(deg, 0, (size_t)NROWS * 2 * sizeof(int), stream);

    prep_w_kernel<<<OUT_F, IN_F, 0, stream>>>(weight, Wt);
    gemm_kernel<<<(N_NODES / 16) * (OUT_F / 16) / 4, 256, 0, stream>>>(x, Wt, bias, h);

    int eBlocks = (nE + 255) / 256;
    count_kernel<<<eBlocks, 256, 0, stream>>>(edge_rows, deg, nE);
    partial_kernel<<<NBLK, 256, 0, stream>>>(deg, partial);
    scan_partial_kernel<<<1, 512, 0, stream>>>(partial, blockoff, row_start, nE);
    scan_rows_kernel<<<NBLK, 256, 0, stream>>>(deg, blockoff, row_start);
    scatter_kernel<<<eBlocks, 256, 0, stream>>>(edge_rows, edge_cols, adj_vals,
                                                row_start, cursor, sorted, nE);
    spmm_csr_kernel<<<NROWS / 4, 256, 0, stream>>>(row_start, sorted, h, out);
}

// Round 3
// 798.190 us; speedup vs baseline: 13.7531x; 1.2626x over previous
//
#include <hip/hip_runtime.h>

#define N_NODES 100000
#define IN_F 256
#define OUT_F 256
#define NROWS N_NODES
#define NBLK ((NROWS + 255) / 256)   // 391 scan blocks
#define MTILES (N_NODES / 16)        // 6250 strips

typedef float f32x4 __attribute__((ext_vector_type(4)));
typedef __bf16 bf16x8 __attribute__((ext_vector_type(8)));
typedef __bf16 bf16x4 __attribute__((ext_vector_type(4)));

// ---------- W transpose + bf16 convert: Wt[n][k] ----------
__global__ __launch_bounds__(256) void prep_w_kernel(const float* __restrict__ W,
                                                     __bf16* __restrict__ Wt) {
    int n = blockIdx.x;
    int k = threadIdx.x;
    Wt[n * IN_F + k] = (__bf16)W[k * OUT_F + n];
}

// ---------- h = x @ W + bias (bf16 out), strip-mined ----------
// One wave computes a 16x256 strip: 16 MFMA tiles sharing one A-fragment.
// x is read exactly once; Wt (128 KB) streams from L2.
// A-frag: x[mt*16 + (lane&15)][k0 + (lane>>4)*8 + j]
// B-frag (tile nt): Wt[nt*16 + (lane&15)][k0 + (lane>>4)*8 + j]
// C/D: row = (lane>>4)*4 + reg, col = lane&15 (within tile)
__global__ __launch_bounds__(256) void gemm_kernel(const float* __restrict__ x,
                                                   const __bf16* __restrict__ Wt,
                                                   const float* __restrict__ bias,
                                                   __bf16* __restrict__ h) {
    int wave = (blockIdx.x << 2) | (threadIdx.x >> 6);
    if (wave >= MTILES) return;
    int lane = threadIdx.x & 63;
    int r16 = lane & 15;
    int quad = lane >> 4;

    const float*  xp = x  + (size_t)(wave * 16 + r16) * IN_F + quad * 8;
    const __bf16* wp = Wt + (size_t)r16 * IN_F + quad * 8;

    f32x4 acc[16];
#pragma unroll
    for (int i = 0; i < 16; ++i) acc[i] = (f32x4){0.f, 0.f, 0.f, 0.f};

#pragma unroll
    for (int k0 = 0; k0 < IN_F; k0 += 32) {
        f32x4 x0 = *(const f32x4*)(xp + k0);
        f32x4 x1 = *(const f32x4*)(xp + k0 + 4);
        bf16x8 a;
        a[0] = (__bf16)x0[0]; a[1] = (__bf16)x0[1];
        a[2] = (__bf16)x0[2]; a[3] = (__bf16)x0[3];
        a[4] = (__bf16)x1[0]; a[5] = (__bf16)x1[1];
        a[6] = (__bf16)x1[2]; a[7] = (__bf16)x1[3];
#pragma unroll
        for (int nt = 0; nt < 16; ++nt) {
            bf16x8 b = *(const bf16x8*)(wp + (size_t)nt * 16 * IN_F + k0);
            acc[nt] = __builtin_amdgcn_mfma_f32_16x16x32_bf16(a, b, acc[nt], 0, 0, 0);
        }
    }

#pragma unroll
    for (int nt = 0; nt < 16; ++nt) {
        float bv = bias[nt * 16 + r16];
        __bf16* hp = h + (size_t)(wave * 16 + quad * 4) * OUT_F + nt * 16 + r16;
#pragma unroll
        for (int r = 0; r < 4; ++r)
            hp[(size_t)r * OUT_F] = (__bf16)(acc[nt][r] + bv);
    }
}

// ---------- CSR build ----------
__global__ __launch_bounds__(256) void count_kernel(const int* __restrict__ rows,
                                                    int* __restrict__ deg, int nE) {
    int e = blockIdx.x * 256 + threadIdx.x;
    if (e < nE) atomicAdd(&deg[rows[e]], 1);
}

__global__ __launch_bounds__(256) void partial_kernel(const int* __restrict__ deg,
                                                      int* __restrict__ partial) {
    __shared__ int s[256];
    int i = blockIdx.x * 256 + threadIdx.x;
    s[threadIdx.x] = (i < NROWS) ? deg[i] : 0;
    __syncthreads();
    for (int d = 128; d > 0; d >>= 1) {
        if (threadIdx.x < d) s[threadIdx.x] += s[threadIdx.x + d];
        __syncthreads();
    }
    if (threadIdx.x == 0) partial[blockIdx.x] = s[0];
}

__global__ __launch_bounds__(512) void scan_partial_kernel(const int* __restrict__ partial,
                                                           int* __restrict__ blockoff,
                                                           int* __restrict__ row_start, int nE) {
    __shared__ int s[512];
    int t = threadIdx.x;
    int v = (t < NBLK) ? partial[t] : 0;
    s[t] = v;
    __syncthreads();
    for (int d = 1; d < 512; d <<= 1) {
        int u = (t >= d) ? s[t - d] : 0;
        __syncthreads();
        s[t] += u;
        __syncthreads();
    }
    if (t < NBLK) blockoff[t] = s[t] - v;   // exclusive block offset
    if (t == 0) row_start[NROWS] = nE;
}

__global__ __launch_bounds__(256) void scan_rows_kernel(const int* __restrict__ deg,
                                                        const int* __restrict__ blockoff,
                                                        int* __restrict__ row_start) {
    __shared__ int s[256];
    int t = threadIdx.x;
    int i = blockIdx.x * 256 + t;
    int v = (i < NROWS) ? deg[i] : 0;
    s[t] = v;
    __syncthreads();
    for (int d = 1; d < 256; d <<= 1) {
        int u = (t >= d) ? s[t - d] : 0;
        __syncthreads();
        s[t] += u;
        __syncthreads();
    }
    if (i < NROWS) row_start[i] = blockoff[blockIdx.x] + s[t] - v;
}

// pos = row_start[r] + (deg[r]-- - 1); reuses deg as a down-cursor.
__global__ __launch_bounds__(256) void scatter_kernel(const int* __restrict__ rows,
                                                      const int* __restrict__ cols,
                                                      const float* __restrict__ vals,
                                                      const int* __restrict__ row_start,
                                                      int* __restrict__ deg,
                                                      int2* __restrict__ sorted, int nE) {
    int e = blockIdx.x * 256 + threadIdx.x;
    if (e >= nE) return;
    int r = rows[e];
    int pos = row_start[r] + atomicSub(&deg[r], 1) - 1;
    sorted[pos] = make_int2(cols[e], __float_as_int(vals[e]));
}

// ---------- SpMM: one wave per row, 8-deep gather pipeline, no atomics ----------
__global__ __launch_bounds__(256) void spmm_csr_kernel(const int* __restrict__ row_start,
                                                       const int2* __restrict__ sorted,
                                                       const __bf16* __restrict__ h,
                                                       float* __restrict__ out) {
    int r = (blockIdx.x << 2) | (threadIdx.x >> 6);
    int lane = threadIdx.x & 63;
    int e0 = row_start[r];
    int e1 = row_start[r + 1];
    f32x4 acc0 = {0.f, 0.f, 0.f, 0.f};
    f32x4 acc1 = {0.f, 0.f, 0.f, 0.f};
    int e = e0;
    for (; e + 8 <= e1; e += 8) {
        int2 cv0 = sorted[e + 0]; int2 cv1 = sorted[e + 1];
        int2 cv2 = sorted[e + 2]; int2 cv3 = sorted[e + 3];
        int2 cv4 = sorted[e + 4]; int2 cv5 = sorted[e + 5];
        int2 cv6 = sorted[e + 6]; int2 cv7 = sorted[e + 7];
        bf16x4 h0 = ((const bf16x4*)(h + (size_t)cv0.x * OUT_F))[lane];
        bf16x4 h1 = ((const bf16x4*)(h + (size_t)cv1.x * OUT_F))[lane];
        bf16x4 h2 = ((const bf16x4*)(h + (size_t)cv2.x * OUT_F))[lane];
        bf16x4 h3 = ((const bf16x4*)(h + (size_t)cv3.x * OUT_F))[lane];
        bf16x4 h4 = ((const bf16x4*)(h + (size_t)cv4.x * OUT_F))[lane];
        bf16x4 h5 = ((const bf16x4*)(h + (size_t)cv5.x * OUT_F))[lane];
        bf16x4 h6 = ((const bf16x4*)(h + (size_t)cv6.x * OUT_F))[lane];
        bf16x4 h7 = ((const bf16x4*)(h + (size_t)cv7.x * OUT_F))[lane];
        float v0 = __int_as_float(cv0.y), v1 = __int_as_float(cv1.y);
        float v2 = __int_as_float(cv2.y), v3 = __int_as_float(cv3.y);
        float v4 = __int_as_float(cv4.y), v5 = __int_as_float(cv5.y);
        float v6 = __int_as_float(cv6.y), v7 = __int_as_float(cv7.y);
#pragma unroll
        for (int j = 0; j < 4; ++j) {
            acc0[j] += v0 * (float)h0[j]; acc1[j] += v1 * (float)h1[j];
            acc0[j] += v2 * (float)h2[j]; acc1[j] += v3 * (float)h3[j];
            acc0[j] += v4 * (float)h4[j]; acc1[j] += v5 * (float)h5[j];
            acc0[j] += v6 * (float)h6[j]; acc1[j] += v7 * (float)h7[j];
        }
    }
    for (; e < e1; ++e) {
        int2 cv = sorted[e];
        float v = __int_as_float(cv.y);
        bf16x4 hv = ((const bf16x4*)(h + (size_t)cv.x * OUT_F))[lane];
#pragma unroll
        for (int j = 0; j < 4; ++j) acc0[j] += v * (float)hv[j];
    }
#pragma unroll
    for (int j = 0; j < 4; ++j) acc0[j] += acc1[j];
    ((f32x4*)(out + (size_t)r * OUT_F))[lane] = acc0;
}

extern "C" void kernel_launch(void* const* d_in, const int* in_sizes, int n_in,
                              void* d_out, int out_size, void* d_ws, size_t ws_size,
                              hipStream_t stream) {
    const float* x         = (const float*)d_in[0];
    const int*   edge_rows = (const int*)d_in[1];
    const int*   edge_cols = (const int*)d_in[2];
    const float* adj_vals  = (const float*)d_in[3];
    const float* weight    = (const float*)d_in[4];
    const float* bias      = (const float*)d_in[5];
    float* out = (float*)d_out;
    int nE = in_sizes[1];

    // ---- workspace layout (~78 MB total) ----
    char* w = (char*)d_ws;
    __bf16* h  = (__bf16*)w;  w += (size_t)N_NODES * OUT_F * sizeof(__bf16);   // 51.2 MB
    __bf16* Wt = (__bf16*)w;  w += (size_t)IN_F * OUT_F * sizeof(__bf16);      // 128 KB
    int* deg       = (int*)w; w += (size_t)NROWS * 4;                          // 400 KB
    int* row_start = (int*)w; w += (size_t)(NROWS + 1) * 4 + 12;               // 400 KB + pad
    int* partial   = (int*)w; w += (size_t)NBLK * 4;
    int* blockoff  = (int*)w; w += (size_t)NBLK * 4 + 8;
    int2* sorted   = (int2*)w;                                                 // 25.6 MB

    hipMemsetAsync(deg, 0, (size_t)NROWS * sizeof(int), stream);

    prep_w_kernel<<<OUT_F, IN_F, 0, stream>>>(weight, Wt);
    gemm_kernel<<<(MTILES + 3) / 4, 256, 0, stream>>>(x, Wt, bias, h);

    int eBlocks = (nE + 255) / 256;
    count_kernel<<<eBlocks, 256, 0, stream>>>(edge_rows, deg, nE);
    partial_kernel<<<NBLK, 256, 0, stream>>>(deg, partial);
    scan_partial_kernel<<<1, 512, 0, stream>>>(partial, blockoff, row_start, nE);
    scan_rows_kernel<<<NBLK, 256, 0, stream>>>(deg, blockoff, row_start);
    scatter_kernel<<<eBlocks, 256, 0, stream>>>(edge_rows, edge_cols, adj_vals,
                                                row_start, deg, sorted, nE);
    spmm_csr_kernel<<<NROWS / 4, 256, 0, stream>>>(row_start, sorted, h, out);
}

// Round 4
// 735.174 us; speedup vs baseline: 14.9320x; 1.0857x over previous
//
#include <hip/hip_runtime.h>

#define N_NODES 100000
#define IN_F 256
#define OUT_F 256
#define NROWS N_NODES
#define NBLK ((NROWS + 255) / 256)   // 391 scan blocks
#define MSTRIPS (N_NODES / 32)       // 3125 strips of 32 rows
#define GEMM_BLOCKS ((MSTRIPS + 3) / 4)  // 782

typedef float f32x4 __attribute__((ext_vector_type(4)));
typedef __bf16 bf16x8 __attribute__((ext_vector_type(8)));

// ---------- W transpose + bf16 convert: Wt[n][k] ----------
__global__ __launch_bounds__(256) void prep_w_kernel(const float* __restrict__ W,
                                                     __bf16* __restrict__ Wt) {
    int n = blockIdx.x;
    int k = threadIdx.x;
    Wt[n * IN_F + k] = (__bf16)W[k * OUT_F + n];
}

// ---------- fused: h = x @ W + bias (blocks < GEMM_BLOCKS) | deg histogram ----------
// GEMM: one wave per 32x256 strip (2 m-tiles x 16 n-tiles). x read once,
// Wt (128 KB) streams from L2 (halved vs 16-row strips).
// A-frag: x[base + m*16 + (lane&15)][k0 + (lane>>4)*8 + j]
// C/D: row = (lane>>4)*4 + reg, col = lane&15.
__global__ __launch_bounds__(256, 2) void gemm_count_kernel(const float* __restrict__ x,
                                                            const __bf16* __restrict__ Wt,
                                                            const float* __restrict__ bias,
                                                            __bf16* __restrict__ h,
                                                            const int* __restrict__ rows,
                                                            int* __restrict__ deg, int nE) {
    if (blockIdx.x >= GEMM_BLOCKS) {
        // ---- degree histogram, 4 edges/thread ----
        int i = (blockIdx.x - GEMM_BLOCKS) * 1024 + threadIdx.x * 4;
        if (i + 3 < nE) {
            int4 rr = *(const int4*)(rows + i);
            atomicAdd(&deg[rr.x], 1);
            atomicAdd(&deg[rr.y], 1);
            atomicAdd(&deg[rr.z], 1);
            atomicAdd(&deg[rr.w], 1);
        } else {
            for (int e = i; e < nE; ++e) atomicAdd(&deg[rows[e]], 1);
        }
        return;
    }

    int wave = (blockIdx.x << 2) | (threadIdx.x >> 6);
    if (wave >= MSTRIPS) return;
    int lane = threadIdx.x & 63;
    int r16 = lane & 15;
    int quad = lane >> 4;

    const float*  xp0 = x + (size_t)(wave * 32 + r16) * IN_F + quad * 8;
    const float*  xp1 = xp0 + (size_t)16 * IN_F;
    const __bf16* wp  = Wt + (size_t)r16 * IN_F + quad * 8;

    f32x4 acc[2][16];
#pragma unroll
    for (int m = 0; m < 2; ++m)
#pragma unroll
        for (int i = 0; i < 16; ++i) acc[m][i] = (f32x4){0.f, 0.f, 0.f, 0.f};

#pragma unroll
    for (int k0 = 0; k0 < IN_F; k0 += 32) {
        f32x4 x00 = *(const f32x4*)(xp0 + k0);
        f32x4 x01 = *(const f32x4*)(xp0 + k0 + 4);
        f32x4 x10 = *(const f32x4*)(xp1 + k0);
        f32x4 x11 = *(const f32x4*)(xp1 + k0 + 4);
        bf16x8 a0, a1;
#pragma unroll
        for (int j = 0; j < 4; ++j) {
            a0[j] = (__bf16)x00[j]; a0[j + 4] = (__bf16)x01[j];
            a1[j] = (__bf16)x10[j]; a1[j + 4] = (__bf16)x11[j];
        }
#pragma unroll
        for (int nt = 0; nt < 16; ++nt) {
            bf16x8 b = *(const bf16x8*)(wp + (size_t)nt * 16 * IN_F + k0);
            acc[0][nt] = __builtin_amdgcn_mfma_f32_16x16x32_bf16(a0, b, acc[0][nt], 0, 0, 0);
            acc[1][nt] = __builtin_amdgcn_mfma_f32_16x16x32_bf16(a1, b, acc[1][nt], 0, 0, 0);
        }
    }

#pragma unroll
    for (int m = 0; m < 2; ++m)
#pragma unroll
        for (int nt = 0; nt < 16; ++nt) {
            float bv = bias[nt * 16 + r16];
            __bf16* hp = h + (size_t)(wave * 32 + m * 16 + quad * 4) * OUT_F + nt * 16 + r16;
#pragma unroll
            for (int r = 0; r < 4; ++r)
                hp[(size_t)r * OUT_F] = (__bf16)(acc[m][nt][r] + bv);
        }
}

// ---------- CSR scan ----------
__global__ __launch_bounds__(256) void partial_kernel(const int* __restrict__ deg,
                                                      int* __restrict__ partial) {
    __shared__ int s[256];
    int i = blockIdx.x * 256 + threadIdx.x;
    s[threadIdx.x] = (i < NROWS) ? deg[i] : 0;
    __syncthreads();
    for (int d = 128; d > 0; d >>= 1) {
        if (threadIdx.x < d) s[threadIdx.x] += s[threadIdx.x + d];
        __syncthreads();
    }
    if (threadIdx.x == 0) partial[blockIdx.x] = s[0];
}

__global__ __launch_bounds__(512) void scan_partial_kernel(const int* __restrict__ partial,
                                                           int* __restrict__ blockoff,
                                                           int* __restrict__ row_start, int nE) {
    __shared__ int s[512];
    int t = threadIdx.x;
    int v = (t < NBLK) ? partial[t] : 0;
    s[t] = v;
    __syncthreads();
    for (int d = 1; d < 512; d <<= 1) {
        int u = (t >= d) ? s[t - d] : 0;
        __syncthreads();
        s[t] += u;
        __syncthreads();
    }
    if (t < NBLK) blockoff[t] = s[t] - v;
    if (t == 0) row_start[NROWS] = nE;
}

__global__ __launch_bounds__(256) void scan_rows_kernel(const int* __restrict__ deg,
                                                        const int* __restrict__ blockoff,
                                                        int* __restrict__ row_start) {
    __shared__ int s[256];
    int t = threadIdx.x;
    int i = blockIdx.x * 256 + t;
    int v = (i < NROWS) ? deg[i] : 0;
    s[t] = v;
    __syncthreads();
    for (int d = 1; d < 256; d <<= 1) {
        int u = (t >= d) ? s[t - d] : 0;
        __syncthreads();
        s[t] += u;
        __syncthreads();
    }
    if (i < NROWS) row_start[i] = blockoff[blockIdx.x] + s[t] - v;
}

// pos = row_start[r] + (deg[r]-- - 1); reuses deg as a down-cursor.
__global__ __launch_bounds__(256) void scatter_kernel(const int* __restrict__ rows,
                                                      const int* __restrict__ cols,
                                                      const float* __restrict__ vals,
                                                      const int* __restrict__ row_start,
                                                      int* __restrict__ deg,
                                                      int2* __restrict__ sorted, int nE) {
    int e = blockIdx.x * 256 + threadIdx.x;
    if (e >= nE) return;
    int r = rows[e];
    int pos = row_start[r] + atomicSub(&deg[r], 1) - 1;
    sorted[pos] = make_int2(cols[e], __float_as_int(vals[e]));
}

// ---------- SpMM: 2 rows/wave (32 lanes/row), 8-deep gather pipeline ----------
__global__ __launch_bounds__(256) void spmm_csr_kernel(const int* __restrict__ row_start,
                                                       const long long* __restrict__ sorted,
                                                       const __bf16* __restrict__ h,
                                                       float* __restrict__ out) {
    int half = threadIdx.x >> 5;           // 0..7 half-waves per block
    int sub  = threadIdx.x & 31;
    int r = blockIdx.x * 8 + half;
    int e0 = row_start[r];
    int e1 = row_start[r + 1];

    f32x4 a0 = {0.f,0.f,0.f,0.f}, a1 = {0.f,0.f,0.f,0.f};   // even edges
    f32x4 b0 = {0.f,0.f,0.f,0.f}, b1 = {0.f,0.f,0.f,0.f};   // odd edges

    int e = e0;
    for (; e + 8 <= e1; e += 8) {
        long long p0 = __builtin_nontemporal_load(sorted + e + 0);
        long long p1 = __builtin_nontemporal_load(sorted + e + 1);
        long long p2 = __builtin_nontemporal_load(sorted + e + 2);
        long long p3 = __builtin_nontemporal_load(sorted + e + 3);
        long long p4 = __builtin_nontemporal_load(sorted + e + 4);
        long long p5 = __builtin_nontemporal_load(sorted + e + 5);
        long long p6 = __builtin_nontemporal_load(sorted + e + 6);
        long long p7 = __builtin_nontemporal_load(sorted + e + 7);
        bf16x8 g0 = ((const bf16x8*)(h + (size_t)(int)p0 * OUT_F))[sub];
        bf16x8 g1 = ((const bf16x8*)(h + (size_t)(int)p1 * OUT_F))[sub];
        bf16x8 g2 = ((const bf16x8*)(h + (size_t)(int)p2 * OUT_F))[sub];
        bf16x8 g3 = ((const bf16x8*)(h + (size_t)(int)p3 * OUT_F))[sub];
        bf16x8 g4 = ((const bf16x8*)(h + (size_t)(int)p4 * OUT_F))[sub];
        bf16x8 g5 = ((const bf16x8*)(h + (size_t)(int)p5 * OUT_F))[sub];
        bf16x8 g6 = ((const bf16x8*)(h + (size_t)(int)p6 * OUT_F))[sub];
        bf16x8 g7 = ((const bf16x8*)(h + (size_t)(int)p7 * OUT_F))[sub];
        float v0 = __int_as_float((int)(p0 >> 32));
        float v1 = __int_as_float((int)(p1 >> 32));
        float v2 = __int_as_float((int)(p2 >> 32));
        float v3 = __int_as_float((int)(p3 >> 32));
        float v4 = __int_as_float((int)(p4 >> 32));
        float v5 = __int_as_float((int)(p5 >> 32));
        float v6 = __int_as_float((int)(p6 >> 32));
        float v7 = __int_as_float((int)(p7 >> 32));
#pragma unroll
        for (int j = 0; j < 4; ++j) {
            a0[j] += v0 * (float)g0[j]; a1[j] += v0 * (float)g0[j + 4];
            b0[j] += v1 * (float)g1[j]; b1[j] += v1 * (float)g1[j + 4];
            a0[j] += v2 * (float)g2[j]; a1[j] += v2 * (float)g2[j + 4];
            b0[j] += v3 * (float)g3[j]; b1[j] += v3 * (float)g3[j + 4];
            a0[j] += v4 * (float)g4[j]; a1[j] += v4 * (float)g4[j + 4];
            b0[j] += v5 * (float)g5[j]; b1[j] += v5 * (float)g5[j + 4];
            a0[j] += v6 * (float)g6[j]; a1[j] += v6 * (float)g6[j + 4];
            b0[j] += v7 * (float)g7[j]; b1[j] += v7 * (float)g7[j + 4];
        }
    }
    for (; e < e1; ++e) {
        long long p = sorted[e];
        float v = __int_as_float((int)(p >> 32));
        bf16x8 g = ((const bf16x8*)(h + (size_t)(int)p * OUT_F))[sub];
#pragma unroll
        for (int j = 0; j < 4; ++j) {
            a0[j] += v * (float)g[j];
            a1[j] += v * (float)g[j + 4];
        }
    }
#pragma unroll
    for (int j = 0; j < 4; ++j) { a0[j] += b0[j]; a1[j] += b1[j]; }
    float* op = out + (size_t)r * OUT_F + sub * 8;
    ((f32x4*)op)[0] = a0;
    ((f32x4*)op)[1] = a1;
}

extern "C" void kernel_launch(void* const* d_in, const int* in_sizes, int n_in,
                              void* d_out, int out_size, void* d_ws, size_t ws_size,
                              hipStream_t stream) {
    const float* x         = (const float*)d_in[0];
    const int*   edge_rows = (const int*)d_in[1];
    const int*   edge_cols = (const int*)d_in[2];
    const float* adj_vals  = (const float*)d_in[3];
    const float* weight    = (const float*)d_in[4];
    const float* bias      = (const float*)d_in[5];
    float* out = (float*)d_out;
    int nE = in_sizes[1];

    // ---- workspace layout (~78 MB total) ----
    char* w = (char*)d_ws;
    __bf16* h  = (__bf16*)w;  w += (size_t)N_NODES * OUT_F * sizeof(__bf16);   // 51.2 MB
    __bf16* Wt = (__bf16*)w;  w += (size_t)IN_F * OUT_F * sizeof(__bf16);      // 128 KB
    int* deg       = (int*)w; w += (size_t)NROWS * 4;
    int* row_start = (int*)w; w += (size_t)(NROWS + 1) * 4 + 12;
    int* partial   = (int*)w; w += (size_t)NBLK * 4;
    int* blockoff  = (int*)w; w += (size_t)NBLK * 4 + 8;
    int2* sorted   = (int2*)w;                                                 // 25.6 MB

    hipMemsetAsync(deg, 0, (size_t)NROWS * sizeof(int), stream);
    prep_w_kernel<<<OUT_F, IN_F, 0, stream>>>(weight, Wt);

    int countBlocks = (nE + 1023) / 1024;
    gemm_count_kernel<<<GEMM_BLOCKS + countBlocks, 256, 0, stream>>>(x, Wt, bias, h,
                                                                     edge_rows, deg, nE);

    partial_kernel<<<NBLK, 256, 0, stream>>>(deg, partial);
    scan_partial_kernel<<<1, 512, 0, stream>>>(partial, blockoff, row_start, nE);
    scan_rows_kernel<<<NBLK, 256, 0, stream>>>(deg, blockoff, row_start);
    int eBlocks = (nE + 255) / 256;
    scatter_kernel<<<eBlocks, 256, 0, stream>>>(edge_rows, edge_cols, adj_vals,
                                                row_start, deg, (int2*)sorted, nE);
    spmm_csr_kernel<<<NROWS / 8, 256, 0, stream>>>(row_start, (const long long*)sorted, h, out);
}